// Round 2
// baseline (12009.128 us; speedup 1.0000x reference)
//
#include <hip/hip_runtime.h>

// ---------------- problem dims ----------------
#define N_SEQ 64
#define T_LEN 512
#define IN_SZ 512
#define HID   1024
#define ODIM  256

// ---------------- config ----------------
#define REC_WGS  128
#define PROJ_WGS 16
#define TOT_WGS  (REC_WGS + PROJ_WGS)
#define BLK      512

// ---------------- ws layout (bytes) ----------------
#define CNT_OFF  0                 // u32 cnt[2][512] arrive counters
#define HBUF_OFF 4096              // 8-slot ring of [64][1024] fp16
#define HSLOT    (N_SEQ * HID)     // halves per slot (65536)

// ---------------- rec LDS layout (bytes) ----------------
#define WF_OFF   0                 // 96 frags x 1024 B (frag-major weights)
#define CB_OFF   98304             // cbuf: [nb][kq-1][slot] x 4096 B (12 bufs)
#define GB_OFF   147456            // gbuf: [nb] x 4096 B
#define BIAS_OFF 155648            // 32 f32
#define FLG_OFF  155776            // lflg[2][4] u32
#define DONE_OFF 155808            // ldone[2] int
#define LDS_BYTES 155904
// proj overlay
#define PW_OFF 0                   // 32 frags x 1024 B
#define PB_OFF 32768               // 16 f32

typedef _Float16 half8  __attribute__((ext_vector_type(8)));
typedef float    f32x4  __attribute__((ext_vector_type(4)));
typedef float    f32x16 __attribute__((ext_vector_type(16)));

union U16B { unsigned long long u[2]; half8 h; };
union U8B  { _Float16 h[4]; unsigned long long u; };

__device__ __forceinline__ float sigmf(float x) { return 1.f / (1.f + expf(-x)); }

// init: zero counters, hb ring slot 7 <- fp16(h0)
__global__ void init_kernel(const float* __restrict__ h0, unsigned char* __restrict__ ws) {
  int idx = blockIdx.x * 256 + threadIdx.x;
  if (idx < 1024) ((unsigned*)ws)[idx] = 0u;   // 4 KB cnt region
  _Float16* h7 = (_Float16*)(ws + HBUF_OFF) + (size_t)7 * HSLOT;
  for (int i = idx; i < N_SEQ * HID; i += gridDim.x * 256) h7[i] = (_Float16)h0[i];
}

__launch_bounds__(BLK, 1)
__global__ void lstm_coop(const float* __restrict__ obs,
                          const float* __restrict__ c0,
                          const float* __restrict__ es,
                          const float* __restrict__ W_ih,
                          const float* __restrict__ W_hh,
                          const float* __restrict__ b_ih,
                          const float* __restrict__ b_hh,
                          const float* __restrict__ W_proj,
                          const float* __restrict__ b_proj,
                          float* __restrict__ out,
                          unsigned char* __restrict__ ws) {
  extern __shared__ char smem[];
  const int tid = threadIdx.x, bid = blockIdx.x;
  const int w = tid >> 6, lane = tid & 63;
  unsigned* cnt = (unsigned*)(ws + CNT_OFF);
  _Float16* hb = (_Float16*)(ws + HBUF_OFF);

  if (bid < REC_WGS) {
    // ============== recurrent role ==============
    _Float16* wf  = (_Float16*)(smem + WF_OFF);
    float* cb     = (float*)(smem + CB_OFF);
    float* gb     = (float*)(smem + GB_OFF);
    float* bias   = (float*)(smem + BIAS_OFF);
    unsigned* lflg= (unsigned*)(smem + FLG_OFF);
    int* ldone    = (int*)(smem + DONE_OFF);

    // stage weights frag-major: frag f (virtual k = f*16), lane l holds
    // B[col = l&31][k = f*16 + (l>>5)*8 + j], contiguous 16 B per lane.
    for (int idx = tid; idx < 96 * 64; idx += BLK) {
      int f = idx >> 6, l = idx & 63;
      int c = l & 31, kg = (l >> 5) * 8;
      int vk = f * 16 + kg;
      int grow = (c >> 3) * HID + bid * 8 + (c & 7);   // gate-major row in 4H
      _Float16* dst = wf + f * 512 + l * 8;
      if (vk < IN_SZ) {
        const float* src = W_ih + (size_t)grow * IN_SZ + vk;
        #pragma unroll
        for (int j = 0; j < 8; ++j) dst[j] = (_Float16)src[j];
      } else {
        const float* src = W_hh + (size_t)grow * HID + (vk - IN_SZ);
        #pragma unroll
        for (int j = 0; j < 8; ++j) dst[j] = (_Float16)src[j];
      }
    }
    if (tid < 32) {
      int grow = (tid >> 3) * HID + bid * 8 + (tid & 7);
      bias[tid] = b_ih[grow] + b_hh[grow];
    }
    if (tid < 8) lflg[tid] = 0u;
    if (tid < 2) ldone[tid] = -1;
    __syncthreads();

    const int nb = w & 1;      // sequence block (32 seqs)
    const int kq = w >> 1;     // 0 = combiner, 1 = x, 2/3 = h halves

    if (kq == 0) {
      // ---------- combiner / epilogue wave ----------
      const int row = lane & 31;
      const int hi  = (row >> 2) & 1;
      const int r_  = (row & 3) + 4 * (row >> 3);
      const int jb  = (lane >> 5) * 4;
      const int n   = nb * 32 + row;
      const int hcb = bid * 8 + jb;
      float cs[4], bb[4][4];
      #pragma unroll
      for (int p = 0; p < 4; ++p) {
        cs[p] = c0[(size_t)n * HID + hcb + p];
        #pragma unroll
        for (int g = 0; g < 4; ++g) bb[g][p] = bias[g * 8 + jb + p];
      }
      float* gbn = gb + nb * 1024;

      for (int t = 0; t < T_LEN; ++t) {
        if (lane == 0) {
          while (__hip_atomic_load(&lflg[nb * 4 + (t & 3)], __ATOMIC_ACQUIRE,
                                   __HIP_MEMORY_SCOPE_WORKGROUP) < 3u)
            __builtin_amdgcn_s_sleep(1);
          __hip_atomic_store(&lflg[nb * 4 + (t & 3)], 0u, __ATOMIC_RELAXED,
                             __HIP_MEMORY_SCOPE_WORKGROUP);
        }
        __asm__ volatile("" ::: "memory");

        // sum 3 partial buffers
        f32x4 s0 = {}, s1 = {}, s2 = {}, s3 = {};
        #pragma unroll
        for (int i = 0; i < 3; ++i) {
          const float* b = cb + (((nb * 3 + i) * 2) + (t & 1)) * 1024 + lane * 16;
          s0 += *(const f32x4*)(b + 0);
          s1 += *(const f32x4*)(b + 4);
          s2 += *(const f32x4*)(b + 8);
          s3 += *(const f32x4*)(b + 12);
        }
        if (lane == 0)
          __hip_atomic_store(&ldone[nb], t, __ATOMIC_RELEASE,
                             __HIP_MEMORY_SCOPE_WORKGROUP);

        // transpose via gbuf: write C-frag layout, gather per (row, hcol)
        *(f32x4*)(gbn + lane * 16 + 0)  = s0;
        *(f32x4*)(gbn + lane * 16 + 4)  = s1;
        *(f32x4*)(gbn + lane * 16 + 8)  = s2;
        *(f32x4*)(gbn + lane * 16 + 12) = s3;
        __asm__ volatile("s_waitcnt lgkmcnt(0)" ::: "memory");

        float m = 1.f - es[(size_t)n * T_LEN + t];
        U8B pk;
        #pragma unroll
        for (int p = 0; p < 4; ++p) {
          int j = jb + p;
          float pi = gbn[((0 * 8 + j) + 32 * hi) * 16 + r_] + bb[0][p];
          float pf = gbn[((1 * 8 + j) + 32 * hi) * 16 + r_] + bb[1][p];
          float pg = gbn[((2 * 8 + j) + 32 * hi) * 16 + r_] + bb[2][p];
          float po = gbn[((3 * 8 + j) + 32 * hi) * 16 + r_] + bb[3][p];
          float cv = sigmf(pf) * (cs[p] * m) + sigmf(pi) * tanhf(pg);
          cs[p] = cv;
          pk.h[p] = (_Float16)(sigmf(po) * tanhf(cv));
        }
        __hip_atomic_store(
            (unsigned long long*)(hb + (size_t)(t & 7) * HSLOT + (size_t)n * HID + hcb),
            pk.u, __ATOMIC_RELAXED, __HIP_MEMORY_SCOPE_AGENT);
        __asm__ volatile("s_waitcnt vmcnt(0)" ::: "memory");
        if (lane == 0)
          __hip_atomic_fetch_add(&cnt[nb * T_LEN + t], 1u, __ATOMIC_RELAXED,
                                 __HIP_MEMORY_SCOPE_AGENT);
      }
    } else {
      // ---------- GEMM writer waves ----------
      const int row = lane & 31, kg = (lane >> 5) * 8;
      const int n = nb * 32 + row;
      const int fbase = (kq - 1) * 32;

      for (int t = 0; t < T_LEN; ++t) {
        if (lane == 0) {
          if (t >= 2)
            while (__hip_atomic_load(&ldone[nb], __ATOMIC_ACQUIRE,
                                     __HIP_MEMORY_SCOPE_WORKGROUP) < t - 1)
              __builtin_amdgcn_s_sleep(1);
          if (kq >= 2 && t >= 1)
            while (__hip_atomic_load(&cnt[nb * T_LEN + t - 1], __ATOMIC_RELAXED,
                                     __HIP_MEMORY_SCOPE_AGENT) < (unsigned)REC_WGS)
              __builtin_amdgcn_s_sleep(2);
        }
        __asm__ volatile("" ::: "memory");

        f32x16 acc = {};
        if (kq == 1) {
          // x part, K=512, fp32->fp16 inline
          const float* xr = obs + ((size_t)n * T_LEN + t) * IN_SZ + kg;
          #pragma unroll 8
          for (int i = 0; i < 32; ++i) {
            f32x4 v0 = *(const f32x4*)(xr + i * 16);
            f32x4 v1 = *(const f32x4*)(xr + i * 16 + 4);
            half8 a;
            a[0] = (_Float16)v0[0]; a[1] = (_Float16)v0[1];
            a[2] = (_Float16)v0[2]; a[3] = (_Float16)v0[3];
            a[4] = (_Float16)v1[0]; a[5] = (_Float16)v1[1];
            a[6] = (_Float16)v1[2]; a[7] = (_Float16)v1[3];
            half8 b = *(const half8*)(wf + i * 512 + lane * 8);
            acc = __builtin_amdgcn_mfma_f32_32x32x16_f16(a, b, acc, 0, 0, 0);
          }
        } else {
          // h part, K=512 half, sc1 loads from ring slot t-1
          float esv = es[(size_t)n * T_LEN + t];
          bool kill = (esv != 0.f);
          const _Float16* hr = hb + (size_t)((t + 7) & 7) * HSLOT +
                               (size_t)n * HID + (kq - 2) * 512 + kg;
          #pragma unroll 8
          for (int i = 0; i < 32; ++i) {
            U16B u;
            u.u[0] = __hip_atomic_load((const unsigned long long*)(hr + i * 16),
                                       __ATOMIC_RELAXED, __HIP_MEMORY_SCOPE_AGENT);
            u.u[1] = __hip_atomic_load((const unsigned long long*)(hr + i * 16 + 4),
                                       __ATOMIC_RELAXED, __HIP_MEMORY_SCOPE_AGENT);
            half8 a = u.h;
            if (kill) a = (half8){};
            half8 b = *(const half8*)(wf + (fbase + i) * 512 + lane * 8);
            acc = __builtin_amdgcn_mfma_f32_32x32x16_f16(a, b, acc, 0, 0, 0);
          }
        }
        float* mycb = cb + (((nb * 3 + (kq - 1)) * 2) + (t & 1)) * 1024 + lane * 16;
        *(f32x4*)(mycb + 0)  = (f32x4){acc[0], acc[1], acc[2], acc[3]};
        *(f32x4*)(mycb + 4)  = (f32x4){acc[4], acc[5], acc[6], acc[7]};
        *(f32x4*)(mycb + 8)  = (f32x4){acc[8], acc[9], acc[10], acc[11]};
        *(f32x4*)(mycb + 12) = (f32x4){acc[12], acc[13], acc[14], acc[15]};
        if (lane == 0)
          __hip_atomic_fetch_add(&lflg[nb * 4 + (t & 3)], 1u, __ATOMIC_RELEASE,
                                 __HIP_MEMORY_SCOPE_WORKGROUP);
      }
    }
  } else {
    // ============== projection role ==============
    _Float16* pw = (_Float16*)(smem + PW_OFF);
    float* pb = (float*)(smem + PB_OFF);
    const int p = bid - REC_WGS;
    const int pbase = p * 16;
    // stage W_proj frag-major for 16x16x32: lane l holds B[col=l&15][k=(l>>4)*8+j]
    for (int idx = tid; idx < 32 * 64; idx += BLK) {
      int f = idx >> 6, l = idx & 63;
      int col = pbase + (l & 15);
      int k0 = f * 32 + (l >> 4) * 8;
      _Float16* dst = pw + f * 512 + l * 8;
      #pragma unroll
      for (int j = 0; j < 8; ++j) dst[j] = (_Float16)W_proj[(size_t)(k0 + j) * ODIM + col];
    }
    if (tid < 16) pb[tid] = b_proj[pbase + tid];
    __syncthreads();

    const int tp = w >> 2, nb = (w >> 1) & 1, rh = w & 1;
    const int rowbase = nb * 32 + rh * 16;
    const int arow = rowbase + (lane & 15);
    const int kg = (lane >> 4) * 8;
    const float bz = pb[lane & 15];

    for (int t = tp; t < T_LEN; t += 2) {
      if (lane == 0)
        while (__hip_atomic_load(&cnt[nb * T_LEN + t], __ATOMIC_RELAXED,
                                 __HIP_MEMORY_SCOPE_AGENT) < (unsigned)REC_WGS)
          __builtin_amdgcn_s_sleep(4);
      __asm__ volatile("" ::: "memory");

      f32x4 acc = {};
      const _Float16* hr = hb + (size_t)(t & 7) * HSLOT + (size_t)arow * HID + kg;
      #pragma unroll 8
      for (int i = 0; i < 32; ++i) {
        U16B u;
        u.u[0] = __hip_atomic_load((const unsigned long long*)(hr + i * 32),
                                   __ATOMIC_RELAXED, __HIP_MEMORY_SCOPE_AGENT);
        u.u[1] = __hip_atomic_load((const unsigned long long*)(hr + i * 32 + 4),
                                   __ATOMIC_RELAXED, __HIP_MEMORY_SCOPE_AGENT);
        half8 b = *(const half8*)(pw + i * 512 + lane * 8);
        acc = __builtin_amdgcn_mfma_f32_16x16x32_f16(u.h, b, acc, 0, 0, 0);
      }
      #pragma unroll
      for (int r = 0; r < 4; ++r) {
        int nn = rowbase + (lane >> 4) * 4 + r;
        out[((size_t)nn * T_LEN + t) * ODIM + pbase + (lane & 15)] = acc[r] + bz;
      }
    }
  }
}

extern "C" void kernel_launch(void* const* d_in, const int* in_sizes, int n_in,
                              void* d_out, int out_size, void* d_ws, size_t ws_size,
                              hipStream_t stream) {
  const float* obs    = (const float*)d_in[0];
  const float* h0     = (const float*)d_in[1];
  const float* c0     = (const float*)d_in[2];
  const float* es     = (const float*)d_in[3];
  const float* W_ih   = (const float*)d_in[4];
  const float* W_hh   = (const float*)d_in[5];
  const float* b_ih   = (const float*)d_in[6];
  const float* b_hh   = (const float*)d_in[7];
  const float* W_proj = (const float*)d_in[8];
  const float* b_proj = (const float*)d_in[9];
  float* out = (float*)d_out;
  unsigned char* ws = (unsigned char*)d_ws;

  hipLaunchKernelGGL(init_kernel, dim3(64), dim3(256), 0, stream, h0, ws);

  hipFuncSetAttribute((const void*)lstm_coop,
                      hipFuncAttributeMaxDynamicSharedMemorySize, LDS_BYTES);

  void* args[] = { (void*)&obs, (void*)&c0, (void*)&es, (void*)&W_ih, (void*)&W_hh,
                   (void*)&b_ih, (void*)&b_hh, (void*)&W_proj, (void*)&b_proj,
                   (void*)&out, (void*)&ws };
  hipLaunchCooperativeKernel((const void*)lstm_coop, dim3(TOT_WGS), dim3(BLK),
                             args, LDS_BYTES, stream);
}